// Round 1
// baseline (1112.421 us; speedup 1.0000x reference)
//
#include <hip/hip_runtime.h>

typedef _Float16 half2_t __attribute__((ext_vector_type(2)));

constexpr int D = 256;
constexpr int NUTT = 64;
constexpr int L = 512;
constexpr int G = 768;           // 3*D
constexpr int KREG = 112;        // half2 pairs (k < 224) held in VGPRs
constexpr int KLDS = 16;         // half2 pairs (k in [224,256)) held in LDS

__device__ __forceinline__ half2_t u2h(unsigned int u) {
  return __builtin_bit_cast(half2_t, u);
}

__device__ __forceinline__ float fdot2(half2_t a, half2_t b, float c) {
#if defined(__has_builtin)
#if __has_builtin(__builtin_amdgcn_fdot2)
  return __builtin_amdgcn_fdot2(a, b, c, false);
#else
  return c + (float)a.x * (float)b.x + (float)a.y * (float)b.y;
#endif
#else
  return c + (float)a.x * (float)b.x + (float)a.y * (float)b.y;
#endif
}

__device__ __forceinline__ float sigm(float x) {
  return 1.0f / (1.0f + __expf(-x));
}
__device__ __forceinline__ float tanh_f(float x) {
  float ax = fabsf(x);
  float e = __expf(-2.0f * ax);
  float r = (1.0f - e) / (1.0f + e);
  return copysignf(r, x);
}

// ---------------------------------------------------------------------------
// Kernel B: gx[m][g] = embed[tokens[m]][:] . Wih[g][:] + bih[g]
// m = b*L + t  (M = 32768), g in [0,768).  Tiled fp32 GEMM, BM=64 BN=128 BK=32
// ---------------------------------------------------------------------------
__global__ __launch_bounds__(256) void gx_gemm(
    const int* __restrict__ tokens, const float* __restrict__ embed,
    const float* __restrict__ Wih, const float* __restrict__ bih,
    float* __restrict__ gx) {
  __shared__ float As[64][33];
  __shared__ float Bs[32][129];
  __shared__ int toks[64];

  const int tid = threadIdx.x;
  const int m0 = blockIdx.x * 64;
  const int n0 = blockIdx.y * 128;
  if (tid < 64) toks[tid] = tokens[m0 + tid];
  __syncthreads();

  const int ty = tid >> 4;   // 0..15 : row group (4 rows each)
  const int tx = tid & 15;   // 0..15 : col base (cols tx + 16*cc)
  float acc[4][8] = {};

  for (int k0 = 0; k0 < 256; k0 += 32) {
    // stage A (embedding gather rows)
    {
      const int i = tid >> 2;            // 0..63
      const int kq = (tid & 3) * 4;      // 0,4,8,12
      const float* src = embed + (size_t)toks[i] * D + k0;
      float4 v0 = *(const float4*)(src + kq);
      float4 v1 = *(const float4*)(src + kq + 16);
      As[i][kq + 0] = v0.x; As[i][kq + 1] = v0.y;
      As[i][kq + 2] = v0.z; As[i][kq + 3] = v0.w;
      As[i][kq + 16] = v1.x; As[i][kq + 17] = v1.y;
      As[i][kq + 18] = v1.z; As[i][kq + 19] = v1.w;
    }
    // stage B (weights, transposed into [k][g])
    {
      const int goff = tid >> 3;         // 0..31
      const int kq = (tid & 7) * 4;      // 0..28
      for (int gp = 0; gp < 128; gp += 32) {
        const float* src = Wih + (size_t)(n0 + goff + gp) * D + k0 + kq;
        float4 v = *(const float4*)src;
        Bs[kq + 0][goff + gp] = v.x;
        Bs[kq + 1][goff + gp] = v.y;
        Bs[kq + 2][goff + gp] = v.z;
        Bs[kq + 3][goff + gp] = v.w;
      }
    }
    __syncthreads();
    const int r0 = ty * 4;
#pragma unroll 4
    for (int k = 0; k < 32; ++k) {
      float a0 = As[r0 + 0][k], a1 = As[r0 + 1][k];
      float a2 = As[r0 + 2][k], a3 = As[r0 + 3][k];
#pragma unroll
      for (int cc = 0; cc < 8; ++cc) {
        float bv = Bs[k][tx + 16 * cc];
        acc[0][cc] = fmaf(a0, bv, acc[0][cc]);
        acc[1][cc] = fmaf(a1, bv, acc[1][cc]);
        acc[2][cc] = fmaf(a2, bv, acc[2][cc]);
        acc[3][cc] = fmaf(a3, bv, acc[3][cc]);
      }
    }
    __syncthreads();
  }
#pragma unroll
  for (int rr = 0; rr < 4; ++rr) {
    float* dst = gx + (size_t)(m0 + ty * 4 + rr) * G + n0;
#pragma unroll
    for (int cc = 0; cc < 8; ++cc) {
      int c = tx + 16 * cc;
      dst[c] = acc[rr][cc] + bih[n0 + c];
    }
  }
}

// ---------------------------------------------------------------------------
// Kernel C: persistent word-GRU scan. 64 WGs (one per utterance) x 768 threads.
// Thread g owns gate-row g of W_hh: 112 half2 in VGPRs + 16 half2 in LDS.
// Per step: gh[g] = W_hh[g,:].h (f16 dot2, fp32 acc); threads d<256 do the
// nonlinear update and write h (f32 + f16 copies) + word_out.
// ---------------------------------------------------------------------------
__global__ __launch_bounds__(768, 3) void gru_scan_word(
    const float* __restrict__ gx,    // [NUTT][L][G] (includes b_ih)
    const float* __restrict__ Whh,   // [G][D]
    const float* __restrict__ bhh,   // [G]
    float* __restrict__ wo) {        // [NUTT][L][D]
  __shared__ __align__(16) half2_t h2s[D / 2];
  __shared__ half2_t wlds[KLDS * G];
  __shared__ float hf[D];
  __shared__ float pre[G];
  __shared__ float xn_s[D];

  const int g = threadIdx.x;
  const int b = blockIdx.x;

  // load this row's weights: k<224 into regs (f16), k in [224,256) into LDS
  half2_t w[KREG];
  const float* wrow = Whh + (size_t)g * D;
#pragma unroll
  for (int c = 0; c < KREG / 2; ++c) {
    float4 v = *(const float4*)(wrow + 4 * c);
    w[2 * c]     = half2_t{(_Float16)v.x, (_Float16)v.y};
    w[2 * c + 1] = half2_t{(_Float16)v.z, (_Float16)v.w};
  }
#pragma unroll
  for (int j = 0; j < KLDS; ++j) {
    float2 v = *(const float2*)(wrow + 2 * KREG + 2 * j);
    wlds[j * G + g] = half2_t{(_Float16)v.x, (_Float16)v.y};
  }
  const float bhh_g = bhh[g];
  if (g < D) hf[g] = 0.0f;
  if (g < D / 2) h2s[g] = half2_t{(_Float16)0.0f, (_Float16)0.0f};

  const float* gxp = gx + (size_t)b * L * G + g;
  float gxv = gxp[0];                          // prefetched gx for step t
  float* wob = wo + (size_t)b * L * D;
  __syncthreads();

  for (int t = 0; t < L; ++t) {
    float gx_next = (t + 1 < L) ? gxp[(size_t)(t + 1) * G] : 0.0f;

    float acc = 0.0f;
    const uint4* hv4 = reinterpret_cast<const uint4*>(h2s);
#pragma unroll
    for (int c = 0; c < KREG / 4; ++c) {       // 28 x (b128 LDS broadcast + 4 dot2)
      uint4 v = hv4[c];
      acc = fdot2(w[4 * c + 0], u2h(v.x), acc);
      acc = fdot2(w[4 * c + 1], u2h(v.y), acc);
      acc = fdot2(w[4 * c + 2], u2h(v.z), acc);
      acc = fdot2(w[4 * c + 3], u2h(v.w), acc);
    }
#pragma unroll
    for (int c = 0; c < KLDS / 4; ++c) {       // LDS-resident weight tail
      uint4 v = hv4[KREG / 4 + c];
      acc = fdot2(wlds[(4 * c + 0) * G + g], u2h(v.x), acc);
      acc = fdot2(wlds[(4 * c + 1) * G + g], u2h(v.y), acc);
      acc = fdot2(wlds[(4 * c + 2) * G + g], u2h(v.z), acc);
      acc = fdot2(wlds[(4 * c + 3) * G + g], u2h(v.w), acc);
    }
    float hg = acc + bhh_g;                    // (h @ Whh^T + bhh)[g]
    if (g < 2 * D) {
      pre[g] = gxv + hg;                       // xr+hr / xz+hz
    } else {
      pre[g] = hg;                             // hn
      xn_s[g - 2 * D] = gxv;                   // xn
    }
    __syncthreads();

    if (g < D) {
      float r = sigm(pre[g]);
      float z = sigm(pre[D + g]);
      float n = tanh_f(xn_s[g] + r * pre[2 * D + g]);
      float hn = fmaf(z, hf[g] - n, n);        // (1-z)*n + z*h
      hf[g] = hn;
      reinterpret_cast<_Float16*>(h2s)[g] = (_Float16)hn;
      wob[(size_t)t * D + g] = hn;
    }
    gxv = gx_next;
    __syncthreads();
  }
}

// ---------------------------------------------------------------------------
// Kernel D: attention pool over word_out -> utt[64][256]
// ---------------------------------------------------------------------------
__global__ __launch_bounds__(256) void attn_pool_word(
    const float* __restrict__ wo, const float* __restrict__ uaw,
    float* __restrict__ utt) {
  __shared__ float wsh[D];
  __shared__ float lg[L];
  __shared__ float red[8];
  const int tid = threadIdx.x, b = blockIdx.x;
  wsh[tid] = uaw[tid];
  __syncthreads();

  const int wid = tid >> 6, lane = tid & 63;
  const float* base = wo + (size_t)b * L * D;
  for (int t = wid; t < L; t += 4) {
    const float* row = base + (size_t)t * D;
    float p = 0.0f;
#pragma unroll
    for (int j = 0; j < 4; ++j) p = fmaf(row[lane + 64 * j], wsh[lane + 64 * j], p);
#pragma unroll
    for (int off = 32; off; off >>= 1) p += __shfl_down(p, off);
    if (lane == 0) lg[t] = p;                  // ua_b cancels in softmax
  }
  __syncthreads();

  float m = fmaxf(lg[tid], lg[tid + 256]);
#pragma unroll
  for (int off = 32; off; off >>= 1) m = fmaxf(m, __shfl_down(m, off));
  if (lane == 0) red[wid] = m;
  __syncthreads();
  m = fmaxf(fmaxf(red[0], red[1]), fmaxf(red[2], red[3]));

  float e0 = __expf(lg[tid] - m), e1 = __expf(lg[tid + 256] - m);
  float s = e0 + e1;
#pragma unroll
  for (int off = 32; off; off >>= 1) s += __shfl_down(s, off);
  if (lane == 0) red[4 + wid] = s;
  __syncthreads();
  s = red[4] + red[5] + red[6] + red[7];
  float inv = 1.0f / s;
  lg[tid] = e0 * inv;
  lg[tid + 256] = e1 * inv;
  __syncthreads();

  float acc = 0.0f;
#pragma unroll 4
  for (int t = 0; t < L; ++t) acc = fmaf(lg[t], base[(size_t)t * D + tid], acc);
  utt[(size_t)b * D + tid] = acc;
}

// ---------------------------------------------------------------------------
// Kernel E: sentence GRU (T=1, h0=0) -> dialog_vec = (1-z)*n
// ---------------------------------------------------------------------------
__global__ __launch_bounds__(256) void sent_kernel(
    const float* __restrict__ utt, const float* __restrict__ Wih,
    const float* __restrict__ bih, const float* __restrict__ bhh,
    float* __restrict__ out) {
  __shared__ float u[D];
  const int d = threadIdx.x, b = blockIdx.x;
  u[d] = utt[(size_t)b * D + d];
  __syncthreads();

  const float* wr = Wih + (size_t)d * D;
  const float* wz = Wih + (size_t)(D + d) * D;
  const float* wn = Wih + (size_t)(2 * D + d) * D;
  float ar = 0.0f, az = 0.0f, an = 0.0f;
  for (int k = 0; k < D; k += 4) {
    float4 vr = *(const float4*)(wr + k);
    float4 vz = *(const float4*)(wz + k);
    float4 vn = *(const float4*)(wn + k);
    float u0 = u[k], u1 = u[k + 1], u2 = u[k + 2], u3 = u[k + 3];
    ar += vr.x * u0 + vr.y * u1 + vr.z * u2 + vr.w * u3;
    az += vz.x * u0 + vz.y * u1 + vz.z * u2 + vz.w * u3;
    an += vn.x * u0 + vn.y * u1 + vn.z * u2 + vn.w * u3;
  }
  float xr = ar + bih[d];
  float xz = az + bih[D + d];
  float xn = an + bih[2 * D + d];
  float r = sigm(xr + bhh[d]);
  float z = sigm(xz + bhh[D + d]);
  float n = tanh_f(xn + r * bhh[2 * D + d]);
  out[(size_t)b * D + d] = (1.0f - z) * n;
}

// ---------------------------------------------------------------------------
extern "C" void kernel_launch(void* const* d_in, const int* in_sizes, int n_in,
                              void* d_out, int out_size, void* d_ws, size_t ws_size,
                              hipStream_t stream) {
  const int* tokens    = (const int*)d_in[0];
  const float* embed   = (const float*)d_in[1];
  const float* wg_Wih  = (const float*)d_in[2];
  const float* wg_Whh  = (const float*)d_in[3];
  const float* wg_bih  = (const float*)d_in[4];
  const float* wg_bhh  = (const float*)d_in[5];
  const float* ua_w    = (const float*)d_in[6];
  // d_in[7] ua_b: softmax shift-invariant -> unused
  const float* sg_Wih  = (const float*)d_in[8];
  // d_in[9] sg_Whh: h0 == 0 -> unused
  const float* sg_bih  = (const float*)d_in[10];
  const float* sg_bhh  = (const float*)d_in[11];
  // d_in[12..13] da_w/da_b: softmax over T=1 -> unused
  float* out = (float*)d_out;

  char* ws = (char*)d_ws;
  float* gx  = (float*)ws;                                     // 96 MB
  float* wo  = (float*)(ws + (size_t)NUTT * L * G * 4);        // 32 MB
  float* utt = (float*)(ws + (size_t)NUTT * L * G * 4
                           + (size_t)NUTT * L * D * 4);        // 64 KB

  dim3 gB(512, 6);
  gx_gemm<<<gB, 256, 0, stream>>>(tokens, embed, wg_Wih, wg_bih, gx);
  gru_scan_word<<<NUTT, G, 0, stream>>>(gx, wg_Whh, wg_bhh, wo);
  attn_pool_word<<<NUTT, 256, 0, stream>>>(wo, ua_w, utt);
  sent_kernel<<<NUTT, 256, 0, stream>>>(utt, sg_Wih, sg_bih, sg_bhh, out);
}